// Round 7
// baseline (97.202 us; speedup 1.0000x reference)
//
#include <hip/hip_runtime.h>
#include <hip/hip_bf16.h>

#define SEQ 4096
#define DIM 512
#define SCALE 0.044194173824159216f  // 1/sqrt(512)

#define SPLITS 4
#define BQ 64
#define KVBLK 32
#define KEYS_PER_SPLIT (SEQ / SPLITS)    // 1024
#define ITERS (KEYS_PER_SPLIT / KVBLK)   // 32
#define THR_DEFER 8.0f

typedef __attribute__((ext_vector_type(8))) short short8;
typedef __attribute__((ext_vector_type(4))) float f32x4;
typedef __attribute__((ext_vector_type(16))) float f32x16;

__device__ __forceinline__ short f2bf(float f) {
  union { float f; unsigned u; } c; c.f = f;
  unsigned u = c.u;
  return (short)((u + 0x7FFFu + ((u >> 16) & 1u)) >> 16);
}

__device__ __forceinline__ short8 pack8(float4 a, float4 b) {
  short8 r;
  r[0] = f2bf(a.x); r[1] = f2bf(a.y); r[2] = f2bf(a.z); r[3] = f2bf(a.w);
  r[4] = f2bf(b.x); r[5] = f2bf(b.y); r[6] = f2bf(b.z); r[7] = f2bf(b.w);
  return r;
}

__device__ __forceinline__ ushort4 pack4(float a, float b, float c, float d) {
  ushort4 r;
  r.x = (unsigned short)f2bf(a); r.y = (unsigned short)f2bf(b);
  r.z = (unsigned short)f2bf(c); r.w = (unsigned short)f2bf(d);
  return r;
}

// async global->LDS, 16B per lane, dest = uniform base + lane*16
__device__ __forceinline__ void gload16(const void* g, void* l) {
  __builtin_amdgcn_global_load_lds(
      (const __attribute__((address_space(1))) unsigned int*)g,
      (__attribute__((address_space(3))) unsigned int*)l, 16, 0, 0);
}

// ---------- prep: fp32 -> bf16 row-major (for K) ----------
__global__ void cvt_bf16(const float* __restrict__ in, ushort* __restrict__ ob, int n8) {
  int i = blockIdx.x * blockDim.x + threadIdx.x;
  if (i >= n8) return;
  const float4* p = (const float4*)(in + (size_t)i * 8);
  short8 v = pack8(p[0], p[1]);
  *(short8*)(ob + (size_t)i * 8) = v;
}

// ---------- prep: fp32 V (S x D) -> bf16 V^T (D x S) ----------
__global__ void transpose_bf16(const float* __restrict__ v, ushort* __restrict__ vt) {
  __shared__ float t[64][65];
  const int bs = blockIdx.x % (SEQ / 64);
  const int bd = blockIdx.x / (SEQ / 64);
  const int s0 = bs * 64, d0 = bd * 64;
  const int tid = threadIdx.x;
#pragma unroll
  for (int k = 0; k < 16; ++k) {
    int idx = k * 256 + tid;
    int r = idx >> 6, c = idx & 63;
    t[r][c] = v[(size_t)(s0 + r) * DIM + d0 + c];
  }
  __syncthreads();
#pragma unroll
  for (int k = 0; k < 16; ++k) {
    int idx = k * 256 + tid;
    int dr = idx >> 6, sc = idx & 63;
    vt[(size_t)(d0 + dr) * SEQ + s0 + sc] = (ushort)f2bf(t[sc][dr]);
  }
}

// ---------- fused attention: 1-tile-ahead pipeline, full double-buffer ----------
// QK role: rg=w&3 (16 q-rows), kh=w>>2 (16-key half). Swapped QK^T -> in-reg SM.
// PV role: rg_pv=w&1 (32 rows), cg=w>>1 (128 cols), 32x32x16 MFMA.
// Per iter: [QK(t+1) MFMA || SM(t) VALU] -> BAR -> PV(t).  2 barriers/iter.
__global__ __launch_bounds__(512, 2) void attn_split(
    const float* __restrict__ q, const ushort* __restrict__ kbf,
    const ushort* __restrict__ vt, float* __restrict__ opart,
    float* __restrict__ ml) {
  __shared__ __align__(16) ushort kt[2][KVBLK * DIM];    // 2x32 KB, g16 ^= row&31
  __shared__ __align__(16) ushort vtt[2][DIM * KVBLK];   // 2x32 KB, g16 ^= row&3
  __shared__ __align__(16) ushort p_lds[2][BQ * KVBLK];  // 2x4 KB,  g16 ^= row&3
  __shared__ float mx_st[2][2][BQ];                      // [tile parity][kh][row]
  __shared__ float osc_st[BQ];
  __shared__ float l_st[2][BQ];
  __shared__ int   flag_st[4];

  const int tid  = threadIdx.x;
  const int lane = tid & 63;
  const int w    = tid >> 6;
  const int lr   = lane & 15;
  const int lg   = lane >> 4;
  const int l31  = lane & 31;
  const int hi   = lane >> 5;
  const int sp   = blockIdx.x & (SPLITS - 1);
  const int qb   = blockIdx.x >> 2;
  const int rg   = w & 3;
  const int kh   = w >> 2;
  const int rg_pv = w & 1;
  const int cg    = w >> 1;
  const int qrow0 = qb * BQ;
  const int kbase = sp * KEYS_PER_SPLIT;

  // Q fragments (B-operand 16x16x32): col=qrow=lr, k=lg*8+j
  short8 qf[16];
  {
    const float* qp = q + (size_t)(qrow0 + rg * 16 + lr) * DIM + lg * 8;
#pragma unroll
    for (int c = 0; c < 16; ++c)
      qf[c] = pack8(*(const float4*)(qp + c * 32), *(const float4*)(qp + c * 32 + 4));
  }
  f32x16 oacc[4] = {};
  float m_reg = -INFINITY, l_reg = 0.f;

  // K rows 1KB: LDS[r][g16] = K[kb+r][(g16 ^ (r&31))*8..]; 4 gloads/wave (1 row ea)
  auto stageK = [&](int kb, int buf) {
#pragma unroll
    for (int i = 0; i < 4; ++i) {
      int r = w * 4 + i;
      const ushort* src = kbf + (size_t)(kb + r) * DIM + ((lane ^ (r & 31)) * 8);
      gload16(src, &kt[buf][r * DIM]);
    }
  };
  // V^T rows 64B (4 granules): LDS[d][g] = vt[d][kb + ((g^(d&3))*8)..]; 4 gloads/wave
  auto stageV = [&](int kb, int buf) {
#pragma unroll
    for (int j = 0; j < 4; ++j) {
      int r0 = w * 64 + j * 16;
      int rr = r0 + (lane >> 2);
      const ushort* src = vt + (size_t)rr * SEQ + kb + (((lane & 3) ^ (rr & 3)) * 8);
      gload16(src, &vtt[buf][r0 * KVBLK]);
    }
  };

  // swapped QK^T on buffer buf: S^T[key=lg*4+r][qrow=lr], 16 keys per wave
  auto qk = [&](int buf) -> f32x4 {
    const int kr = kh * 16 + lr;
    const char* krow = (const char*)&kt[buf][kr * DIM];
    f32x4 s = {};
    __builtin_amdgcn_s_setprio(1);
#pragma unroll
    for (int c = 0; c < 16; ++c) {
      short8 k0 = *(const short8*)(krow + (((c * 4 + lg) ^ kr) << 4));
      s = __builtin_amdgcn_mfma_f32_16x16x32_bf16(k0, qf[c], s, 0, 0, 0);
    }
    __builtin_amdgcn_s_setprio(0);
    return s;
  };

  // ---- prologue: K(0), V(0), K(1) in flight; QK(0) ----
  stageK(kbase, 0);
  stageV(kbase, 0);
  stageK(kbase + KVBLK, 1);
  asm volatile("s_waitcnt vmcnt(8)" ::: "memory");  // K(0) landed (V0+K1 = 8 out)
  __builtin_amdgcn_s_barrier();

  float scA[4];
  {
    f32x4 s = qk(0);
#pragma unroll
    for (int r = 0; r < 4; ++r) scA[r] = s[r] * SCALE;
    float tm = fmaxf(fmaxf(scA[0], scA[1]), fmaxf(scA[2], scA[3]));
    tm = fmaxf(tm, __shfl_xor(tm, 16));
    tm = fmaxf(tm, __shfl_xor(tm, 32));
    if (lane < 16) mx_st[0][kh][rg * 16 + lane] = tm;
  }
  asm volatile("s_waitcnt lgkmcnt(0)" ::: "memory");
  __builtin_amdgcn_s_barrier();

#pragma unroll 1
  for (int t = 0; t < ITERS; ++t) {
    const int cur = t & 1, nxt = cur ^ 1;
    const bool have_next = (t + 1 < ITERS);

    // drain own K(t+1)+V(t) (issued last iter), then cross-wave barrier
    asm volatile("s_waitcnt vmcnt(0)" ::: "memory");
    __builtin_amdgcn_s_barrier();  // BAR-top: kt[nxt], vtt[cur] visible

    // ---- QK(t+1) MFMA (independent) runs alongside SM(t) VALU ----
    f32x4 sN = {};
    if (have_next) sN = qk(nxt);

    // ---- SM(t): common m across kh pair, defer-max, P -> p_lds[cur] ----
    {
      const int row = rg * 16 + lr;
      float tmax64 = fmaxf(mx_st[cur][0][row], mx_st[cur][1][row]);
      bool resc = tmax64 > m_reg + THR_DEFER;
      float mnew = resc ? tmax64 : m_reg;
      float osc = __expf(m_reg - mnew);  // 1.0 deferred; 0 on first tile
      unsigned long long bl = __ballot(resc);
      if (kh == 0 && lane == 0) flag_st[rg] = (bl != 0ull) ? 1 : 0;
      if (kh == 0 && lane < 16) osc_st[row] = osc;
      m_reg = mnew;
      l_reg *= osc;
      float p0[4];
#pragma unroll
      for (int r = 0; r < 4; ++r) p0[r] = __expf(scA[r] - m_reg);
      float ps = (p0[0] + p0[1]) + (p0[2] + p0[3]);
      ps += __shfl_xor(ps, 16);
      ps += __shfl_xor(ps, 32);
      l_reg += ps;
      char* pb = (char*)&p_lds[cur][row * KVBLK];
      *(ushort4*)(pb + ((kh * 32 + lg * 8) ^ ((row & 3) << 4))) =
          pack4(p0[0], p0[1], p0[2], p0[3]);
    }

    // ---- finish tile t+1 pre-softmax; issue next stages ----
    if (have_next) {
#pragma unroll
      for (int r = 0; r < 4; ++r) scA[r] = sN[r] * SCALE;
      float tm = fmaxf(fmaxf(scA[0], scA[1]), fmaxf(scA[2], scA[3]));
      tm = fmaxf(tm, __shfl_xor(tm, 16));
      tm = fmaxf(tm, __shfl_xor(tm, 32));
      if (lane < 16) mx_st[nxt][kh][rg * 16 + lane] = tm;
      if (t + 2 < ITERS) stageK(kbase + (t + 2) * KVBLK, cur);
      stageV(kbase + (t + 1) * KVBLK, nxt);
    }

    asm volatile("s_waitcnt lgkmcnt(0)" ::: "memory");  // P(t)/mx(t+1) visible
    __builtin_amdgcn_s_barrier();                       // BAR-mid

    // ---- PV(t) (32x32x16): rows rg_pv*32.., cols cg*128.. ----
    {
      if (flag_st[rg_pv * 2] | flag_st[rg_pv * 2 + 1]) {
        float ov[16];
#pragma unroll
        for (int r = 0; r < 16; ++r)
          ov[r] = osc_st[rg_pv * 32 + (r & 3) + 8 * (r >> 2) + 4 * hi];
#pragma unroll
        for (int t4 = 0; t4 < 4; ++t4)
#pragma unroll
          for (int r = 0; r < 16; ++r) oacc[t4][r] *= ov[r];
      }
      const int arow = rg_pv * 32 + l31;
      const char* prow = (const char*)&p_lds[cur][arow * KVBLK];
      const int psw = (arow & 3) << 4;
      __builtin_amdgcn_s_setprio(1);
#pragma unroll
      for (int c = 0; c < 2; ++c) {
        short8 pa = *(const short8*)(prow + ((c * 32 + hi * 16) ^ psw));
#pragma unroll
        for (int t4 = 0; t4 < 4; ++t4) {
          int vrow = cg * 128 + t4 * 32 + l31;
          short8 vf = *(const short8*)((const char*)&vtt[cur][vrow * KVBLK] +
                                       ((c * 32 + hi * 16) ^ ((vrow & 3) << 4)));
          oacc[t4] = __builtin_amdgcn_mfma_f32_32x32x16_bf16(pa, vf, oacc[t4], 0, 0, 0);
        }
      }
      __builtin_amdgcn_s_setprio(0);
    }
  }

  // ---- epilogue: merge l across kh, write opart + ml ----
  if (lane < 16) {
    l_st[kh][rg * 16 + lane] = l_reg;
    if (kh == 0) mx_st[0][0][rg * 16 + lane] = m_reg;
  }
  __syncthreads();
  {
    float* op = opart + ((size_t)sp * SEQ + qrow0 + rg_pv * 32) * DIM + cg * 128;
#pragma unroll
    for (int t4 = 0; t4 < 4; ++t4)
#pragma unroll
      for (int r = 0; r < 16; ++r) {
        int crow = (r & 3) + 8 * (r >> 2) + 4 * hi;
        op[(size_t)crow * DIM + t4 * 32 + l31] = oacc[t4][r];
      }
  }
  if (tid < BQ) {
    size_t base = ((size_t)sp * SEQ + qrow0 + tid) * 2;
    ml[base]     = mx_st[0][0][tid];
    ml[base + 1] = l_st[0][tid] + l_st[1][tid];
  }
}

// ---------- combine split partials ----------
__global__ void combine(const float* __restrict__ opart, const float* __restrict__ ml,
                        float* __restrict__ out) {
  int gid = blockIdx.x * 256 + threadIdx.x;
  int row = gid >> 7;
  int dv  = (gid & 127) * 4;
  float m[SPLITS], l[SPLITS], wgt[SPLITS];
  float M = -INFINITY;
#pragma unroll
  for (int i = 0; i < SPLITS; ++i) {
    m[i] = ml[((size_t)i * SEQ + row) * 2];
    l[i] = ml[((size_t)i * SEQ + row) * 2 + 1];
    M = fmaxf(M, m[i]);
  }
  float L = 0.f;
#pragma unroll
  for (int i = 0; i < SPLITS; ++i) { wgt[i] = __expf(m[i] - M); L += l[i] * wgt[i]; }
  float inv = 1.f / L;
  float4 acc = {0.f, 0.f, 0.f, 0.f};
#pragma unroll
  for (int i = 0; i < SPLITS; ++i) {
    float4 o = *(const float4*)(opart + ((size_t)i * SEQ + row) * DIM + dv);
    acc.x += o.x * wgt[i]; acc.y += o.y * wgt[i];
    acc.z += o.z * wgt[i]; acc.w += o.w * wgt[i];
  }
  acc.x *= inv; acc.y *= inv; acc.z *= inv; acc.w *= inv;
  *(float4*)(out + (size_t)row * DIM + dv) = acc;
}

// ---------- fallback if ws too small ----------
__global__ __launch_bounds__(512) void attn_fused_fb(
    const float* __restrict__ q, const float* __restrict__ k,
    const float* __restrict__ v, float* __restrict__ out) {
  __shared__ float s_lds[16][128];
  __shared__ __align__(16) unsigned short p_lds[16 * 128];
  __shared__ float m_st[16], l_st[16], osc_st[16];
  const int tid = threadIdx.x, lane = tid & 63, w = tid >> 6;
  const int lr = lane & 15, lg = lane >> 4, qb = blockIdx.x * 16;
  if (tid < 16) { m_st[tid] = -INFINITY; l_st[tid] = 0.f; }
  short8 qf[16];
  {
    const float* qp = q + (size_t)(qb + lr) * DIM + lg * 8;
#pragma unroll
    for (int c = 0; c < 16; ++c)
      qf[c] = pack8(*(const float4*)(qp + c * 32), *(const float4*)(qp + c * 32 + 4));
  }
  f32x4 oacc[4] = {};
  __syncthreads();
  for (int it = 0; it < SEQ / 128; ++it) {
    const int kb = it * 128;
    {
      const float* kp = k + (size_t)(kb + w * 16 + lr) * DIM + lg * 8;
      f32x4 sacc = {};
#pragma unroll
      for (int c = 0; c < 16; ++c) {
        short8 kf = pack8(*(const float4*)(kp + c * 32), *(const float4*)(kp + c * 32 + 4));
        sacc = __builtin_amdgcn_mfma_f32_16x16x32_bf16(qf[c], kf, sacc, 0, 0, 0);
      }
#pragma unroll
      for (int r = 0; r < 4; ++r) s_lds[lg * 4 + r][w * 16 + lr] = sacc[r] * SCALE;
    }
    __syncthreads();
    {
      const int srow = tid >> 5, sj = tid & 31;
      float4 sv = *(const float4*)&s_lds[srow][sj * 4];
      float tmax = fmaxf(fmaxf(sv.x, sv.y), fmaxf(sv.z, sv.w));
#pragma unroll
      for (int m = 16; m >= 1; m >>= 1) tmax = fmaxf(tmax, __shfl_xor(tmax, m));
      float mold = m_st[srow], mnew = fmaxf(mold, tmax);
      float p0 = __expf(sv.x - mnew), p1 = __expf(sv.y - mnew);
      float p2 = __expf(sv.z - mnew), p3 = __expf(sv.w - mnew);
      float psum = (p0 + p1) + (p2 + p3);
#pragma unroll
      for (int m = 16; m >= 1; m >>= 1) psum += __shfl_xor(psum, m);
      if (sj == 0) {
        float sc = __expf(mold - mnew);
        l_st[srow] = l_st[srow] * sc + psum; m_st[srow] = mnew; osc_st[srow] = sc;
      }
      ushort4 pb;
      pb.x = (unsigned short)f2bf(p0); pb.y = (unsigned short)f2bf(p1);
      pb.z = (unsigned short)f2bf(p2); pb.w = (unsigned short)f2bf(p3);
      int lin = srow * 256 + sj * 8;
      *(ushort4*)((char*)p_lds + (lin ^ ((srow & 7) << 4))) = pb;
    }
    __syncthreads();
    {
      float osc[4];
#pragma unroll
      for (int r = 0; r < 4; ++r) osc[r] = osc_st[lg * 4 + r];
#pragma unroll
      for (int ct = 0; ct < 4; ++ct)
#pragma unroll
        for (int r = 0; r < 4; ++r) oacc[ct][r] *= osc[r];
#pragma unroll
      for (int kc = 0; kc < 4; ++kc) {
        int lin = lr * 256 + (kc * 32 + 8 * lg) * 2;
        short8 pf = *(const short8*)((const char*)p_lds + (lin ^ ((lr & 7) << 4)));
        const float* vp0 = v + (size_t)(kb + kc * 32 + 8 * lg) * DIM + w * 64 + lr;
#pragma unroll
        for (int ct = 0; ct < 4; ++ct) {
          const float* vp = vp0 + ct * 16;
          short8 vf;
#pragma unroll
          for (int jj = 0; jj < 8; ++jj) vf[jj] = f2bf(vp[(size_t)jj * DIM]);
          oacc[ct] = __builtin_amdgcn_mfma_f32_16x16x32_bf16(pf, vf, oacc[ct], 0, 0, 0);
        }
      }
    }
    __syncthreads();
  }
  {
    float linv[4];
#pragma unroll
    for (int r = 0; r < 4; ++r) linv[r] = 1.f / l_st[lg * 4 + r];
#pragma unroll
    for (int ct = 0; ct < 4; ++ct)
#pragma unroll
      for (int r = 0; r < 4; ++r)
        out[(size_t)(qb + lg * 4 + r) * DIM + w * 64 + ct * 16 + lr] =
            oacc[ct][r] * linv[r];
  }
}

extern "C" void kernel_launch(void* const* d_in, const int* in_sizes, int n_in,
                              void* d_out, int out_size, void* d_ws, size_t ws_size,
                              hipStream_t stream) {
  (void)in_sizes; (void)n_in; (void)out_size;
  const float* q = (const float*)d_in[0];
  const float* k = (const float*)d_in[1];
  const float* v = (const float*)d_in[2];
  float* out = (float*)d_out;

  const size_t kbf_elems = (size_t)SEQ * DIM;
  const size_t vt_elems  = (size_t)DIM * SEQ;
  const size_t op_elems  = (size_t)SPLITS * SEQ * DIM;
  const size_t ml_elems  = (size_t)SPLITS * SEQ * 2;
  const size_t need = kbf_elems * 2 + vt_elems * 2 + op_elems * 4 + ml_elems * 4;

  if (ws_size >= need) {
    ushort* kbf  = (ushort*)d_ws;
    ushort* vtb  = kbf + kbf_elems;
    float* opart = (float*)(vtb + vt_elems);
    float* ml    = opart + op_elems;

    cvt_bf16<<<(SEQ * DIM / 8 + 255) / 256, 256, 0, stream>>>(k, kbf, SEQ * DIM / 8);
    transpose_bf16<<<(SEQ / 64) * (DIM / 64), 256, 0, stream>>>(v, vtb);
    attn_split<<<(SEQ / BQ) * SPLITS, 512, 0, stream>>>(q, kbf, vtb, opart, ml);
    combine<<<(SEQ * DIM / 4) / 256, 256, 0, stream>>>(opart, ml, out);
  } else {
    attn_fused_fb<<<SEQ / 16, 512, 0, stream>>>(q, k, v, out);
  }
}